// Round 1
// baseline (166.901 us; speedup 1.0000x reference)
//
#include <hip/hip_runtime.h>
#include <math.h>

#define KK 32
#define CC 256

// ---------------------------------------------------------------------------
// Kernel 1: per-(b,m) stats. 256 blocks (one per b,m), 256 threads.
//  - stage x[b,m] (32x256) in LDS (row stride 257 -> conflict-free)
//  - row sums / means
//  - cov (ref order: (xi-mi)*(xj-mj)), eqsum for the pos==1 diagonal-equality
//  - write pooled into p_ws in [b][i*32+j][m] layout (GEMM-ready)
//  - write adj = cov/(std_i*std_j) straight to d_out's second output region
// ---------------------------------------------------------------------------
__global__ __launch_bounds__(256) void prep_kernel(
    const float* __restrict__ x, float* __restrict__ p_ws,
    float* __restrict__ adj_out)
{
    const int bm = blockIdx.x;            // 0..255
    const int b  = bm >> 6, m = bm & 63;
    __shared__ float xs[KK][CC + 1];
    __shared__ float part8[256];
    __shared__ float rowsum[KK];
    __shared__ float meanv[KK];
    __shared__ float covm[KK][KK + 1];
    __shared__ float stdv[KK];

    const int t = threadIdx.x;
    const float* xp = x + (size_t)bm * (KK * CC);
    for (int idx = t; idx < KK * CC; idx += 256)
        xs[idx >> 8][idx & 255] = xp[idx];
    __syncthreads();

    // row sums: 8 partials per row, then reduce
    {
        const int i = t >> 3, part = t & 7;
        float s = 0.f;
        const int c0 = part * 32;
        #pragma unroll
        for (int c = 0; c < 32; ++c) s += xs[i][c0 + c];
        part8[t] = s;
    }
    __syncthreads();
    if (t < KK) {
        float s = 0.f;
        #pragma unroll
        for (int k = 0; k < 8; ++k) s += part8[t * 8 + k];
        rowsum[t] = s;
        meanv[t]  = s * (1.0f / CC);
    }
    __syncthreads();

    // each thread handles 4 (i,j) pairs
    #pragma unroll
    for (int k = 0; k < 4; ++k) {
        const int pair = t + k * 256;
        const int i = pair >> 5, j = pair & 31;
        const float mi = meanv[i], mj = meanv[j];
        float cv = 0.f, eq = 0.f;
        for (int c = 0; c < CC; ++c) {
            const float xi = xs[i][c], xj = xs[j][c];
            cv += (xi - mi) * (xj - mj);
            eq += (xi == xj) ? xj : 0.f;   // pos==1 exactly where floats equal
        }
        cv *= (1.0f / (CC - 1));
        covm[i][j] = cv;
        // pooled = 0.5*(mean_i + mean_c(pos*xj)) ; pos*xj = 2*xj - [eq]*xj
        const float pooled = 0.5f * (mi + (2.f * rowsum[j] - eq) * (1.0f / CC));
        p_ws[((size_t)(b * 1024 + pair)) * 64 + m] = pooled;
    }
    __syncthreads();
    if (t < KK) stdv[t] = sqrtf(covm[t][t]);
    __syncthreads();
    #pragma unroll
    for (int k = 0; k < 4; ++k) {
        const int pair = t + k * 256;
        const int i = pair >> 5, j = pair & 31;
        adj_out[(size_t)bm * 1024 + pair] = covm[i][j] / (stdv[i] * stdv[j]);
    }
}

// ---------------------------------------------------------------------------
// Kernel 2: h = gelu(W1 @ p).  block (64m x 4o): each wave = one o, 64 m.
// W1[o,c] is wave-uniform (s_load), p reads coalesced across m.
// ---------------------------------------------------------------------------
__global__ __launch_bounds__(256) void mlp1_kernel(
    const float* __restrict__ W1, const float* __restrict__ p_ws,
    float* __restrict__ h_ws)
{
    const int m = threadIdx.x;                       // 0..63
    const int o = blockIdx.x * 4 + threadIdx.y;      // 0..511
    const int b = blockIdx.y;
    const float* w  = W1 + (size_t)o * 1024;
    const float* pb = p_ws + (size_t)b * (1024 * 64) + m;
    float acc0 = 0.f, acc1 = 0.f;
    #pragma unroll 8
    for (int c = 0; c < 1024; c += 2) {
        acc0 += w[c]     * pb[(size_t)c * 64];
        acc1 += w[c + 1] * pb[(size_t)(c + 1) * 64];
    }
    const float a = acc0 + acc1;
    const float g = 0.5f * a * (1.0f + erff(a * 0.70710678118654752f));
    h_ws[((size_t)(b * 512 + o)) * 64 + m] = g;
}

// ---------------------------------------------------------------------------
// Kernel 3: e = sigmoid(W2 @ h). Same structure, K=512, o in 0..1023.
// ---------------------------------------------------------------------------
__global__ __launch_bounds__(256) void mlp2_kernel(
    const float* __restrict__ W2, const float* __restrict__ h_ws,
    float* __restrict__ e_ws)
{
    const int m = threadIdx.x;
    const int o = blockIdx.x * 4 + threadIdx.y;      // 0..1023
    const int b = blockIdx.y;
    const float* w  = W2 + (size_t)o * 512;
    const float* hb = h_ws + (size_t)b * (512 * 64) + m;
    float acc0 = 0.f, acc1 = 0.f;
    #pragma unroll 8
    for (int c = 0; c < 512; c += 2) {
        acc0 += w[c]     * hb[(size_t)c * 64];
        acc1 += w[c + 1] * hb[(size_t)(c + 1) * 64];
    }
    const float a = acc0 + acc1;
    const float e = 1.0f / (1.0f + expf(-a));
    e_ws[((size_t)(b * 1024 + o)) * 64 + m] = e;
}

// ---------------------------------------------------------------------------
// Kernel 4: masked softmax (mask adj>0; diagonal always survives) + att @ x.
// 256 blocks (b,m), 256 threads. exp(-inf)==0 matches ref's -9e15 underflow.
// ---------------------------------------------------------------------------
__global__ __launch_bounds__(256) void softmax_out_kernel(
    const float* __restrict__ x, const float* __restrict__ e_ws,
    const float* __restrict__ adj, float* __restrict__ out)
{
    const int bm = blockIdx.x;
    const int b  = bm >> 6, m = bm & 63;
    __shared__ float xs[KK][CC + 1];
    __shared__ float att[KK][KK + 1];
    const int t = threadIdx.x;
    const float* xp = x + (size_t)bm * (KK * CC);
    for (int idx = t; idx < KK * CC; idx += 256)
        xs[idx >> 8][idx & 255] = xp[idx];
    #pragma unroll
    for (int k = 0; k < 4; ++k) {
        const int pair = t + k * 256;
        const int i = pair >> 5, j = pair & 31;
        const float a  = adj[(size_t)bm * 1024 + pair];
        const float ev = e_ws[((size_t)(b * 1024 + pair)) * 64 + m];
        att[i][j] = (a > 0.f) ? ev : -INFINITY;
    }
    __syncthreads();
    if (t < KK) {
        float mx = -INFINITY;
        #pragma unroll
        for (int j = 0; j < KK; ++j) mx = fmaxf(mx, att[t][j]);
        float s = 0.f;
        #pragma unroll
        for (int j = 0; j < KK; ++j) {
            const float v = expf(att[t][j] - mx);
            att[t][j] = v;
            s += v;
        }
        const float inv = 1.0f / s;
        #pragma unroll
        for (int j = 0; j < KK; ++j) att[t][j] *= inv;
    }
    __syncthreads();
    const int c = t;  // 0..255 == C
    float* op = out + (size_t)bm * (KK * CC) + c;
    #pragma unroll 4
    for (int i = 0; i < KK; ++i) {
        float s = 0.f;
        #pragma unroll
        for (int j = 0; j < KK; ++j) s += att[i][j] * xs[j][c];
        op[(size_t)i * CC] = s;
    }
}

extern "C" void kernel_launch(void* const* d_in, const int* in_sizes, int n_in,
                              void* d_out, int out_size, void* d_ws, size_t ws_size,
                              hipStream_t stream) {
    const float* x  = (const float*)d_in[0];   // (4,64,32,256)
    const float* W1 = (const float*)d_in[1];   // (512,1024)
    const float* W2 = (const float*)d_in[2];   // (1024,512)
    float* out     = (float*)d_out;                       // 2,097,152 floats
    float* adj_out = out + (size_t)4 * 64 * 32 * 256;     // +262,144 floats

    float* p_ws = (float*)d_ws;                 // 4*1024*64 = 262,144 floats
    float* h_ws = p_ws + (size_t)4 * 1024 * 64; // 4*512*64  = 131,072 floats
    float* e_ws = h_ws + (size_t)4 * 512 * 64;  // 4*1024*64 = 262,144 floats

    prep_kernel<<<256, 256, 0, stream>>>(x, p_ws, adj_out);
    mlp1_kernel<<<dim3(128, 4), dim3(64, 4), 0, stream>>>(W1, p_ws, h_ws);
    mlp2_kernel<<<dim3(256, 4), dim3(64, 4), 0, stream>>>(W2, h_ws, e_ws);
    softmax_out_kernel<<<256, 256, 0, stream>>>(x, e_ws, adj_out, out);
}

// Round 2
// 107.750 us; speedup vs baseline: 1.5490x; 1.5490x over previous
//
#include <hip/hip_runtime.h>
#include <math.h>

#define KK 32
#define CC 256

// ---------------------------------------------------------------------------
// Kernel 1 (fused): blocks 0..255 = per-(b,m) stats; blocks 256..767 = A-transform.
//
// Stats: stage x[b,m] (32x256) in LDS, row means, center, cov upper-tri via
// 2x2 register tiles (BIT-EXACT sequential fma chain per (i,j) — the adj>0
// mask is knife-edge, do NOT reassociate), adj to global, means to mean_ws.
//
// A-transform: A[o,k] = 0.5*rowsum_k(W1 row o) + colsum_k - 0.5*W1[o,33k],
// so that W1 @ p == A @ mean  (pooled_ij = (i==j)? m_i : 0.5*m_i + m_j).
// ---------------------------------------------------------------------------
__global__ __launch_bounds__(256) void prep_kernel(
    const float* __restrict__ x, const float* __restrict__ W1,
    float* __restrict__ mean_ws, float* __restrict__ A_ws,
    float* __restrict__ adj_out)
{
    __shared__ float xs[KK][258];      // 33 KB, stride 258: float2-aligned, 2-way banks
    __shared__ float part8[256];
    __shared__ float meanv[KK];
    __shared__ float covm[KK][KK + 1];
    __shared__ float stdv[KK];
    __shared__ float rowlds[1056];     // A-part: padded W1 row (33-stride 32-blocks)

    const int t = threadIdx.x;

    if (blockIdx.x >= 256) {
        // ---------------- A-transform: one W1 row per block ----------------
        const int o = blockIdx.x - 256;           // 0..511
        if (t < 64) {
            const float* wr = W1 + (size_t)o * 1024;
            #pragma unroll
            for (int u = 0; u < 4; ++u) {
                const int e = t * 16 + u * 4;
                const float4 v = *(const float4*)(wr + e);
                const int f = (e >> 5) * 33 + (e & 31);
                rowlds[f] = v.x; rowlds[f + 1] = v.y;
                rowlds[f + 2] = v.z; rowlds[f + 3] = v.w;
            }
        }
        __syncthreads();
        if (t < 32) {
            float rs = 0.f, cs = 0.f;
            #pragma unroll
            for (int j = 0; j < 32; ++j) rs += rowlds[t * 33 + j];
            #pragma unroll
            for (int i = 0; i < 32; ++i) cs += rowlds[i * 33 + t];
            const float diag = rowlds[t * 34];
            A_ws[o * 32 + t] = 0.5f * rs + cs - 0.5f * diag;
        }
        return;
    }

    // ---------------- per-(b,m) stats ----------------
    const int bm = blockIdx.x;            // 0..255
    const int b  = bm >> 6, m = bm & 63;
    const float* xp = x + (size_t)bm * (KK * CC);

    // stage: float4 global loads, scalar LDS stores (stride 258)
    #pragma unroll
    for (int s = 0; s < 8; ++s) {
        const int e = s * 1024 + t * 4;
        const float4 v = *(const float4*)(xp + e);
        const int i = e >> 8, col = e & 255;
        xs[i][col] = v.x; xs[i][col + 1] = v.y;
        xs[i][col + 2] = v.z; xs[i][col + 3] = v.w;
    }
    __syncthreads();

    // row sums -> means (identical reduction structure to the passing v1)
    {
        const int i = t >> 3, part = t & 7;
        float s = 0.f;
        const int c0 = part * 32;
        #pragma unroll
        for (int c = 0; c < 32; ++c) s += xs[i][c0 + c];
        part8[t] = s;
    }
    __syncthreads();
    if (t < KK) {
        float s = 0.f;
        #pragma unroll
        for (int k = 0; k < 8; ++k) s += part8[t * 8 + k];
        meanv[t] = s * (1.0f / CC);
        mean_ws[(size_t)(b * 32 + t) * 64 + m] = meanv[t];
    }
    __syncthreads();

    // center rows in place: cen = x - mean (same rounding as inline (xi-mi))
    {
        const int r = t >> 3, c0 = (t & 7) * 32;
        const float mv = meanv[r];
        #pragma unroll
        for (int c = 0; c < 32; ++c) xs[r][c0 + c] -= mv;
    }
    __syncthreads();

    // cov upper-triangle: 136 2x2 tiles, one per thread (t<136)
    if (t < 136) {
        int rem = t, r = 0;
        while (rem >= 16 - r) { rem -= 16 - r; ++r; }
        const int ti = r, tj = r + rem;
        const int i0 = 2 * ti, i1 = i0 + 1, j0 = 2 * tj, j1 = j0 + 1;
        float c00 = 0.f, c01 = 0.f, c10 = 0.f, c11 = 0.f;
        for (int c = 0; c < CC; c += 2) {
            const float2 a0 = *(const float2*)&xs[i0][c];
            const float2 a1 = *(const float2*)&xs[i1][c];
            const float2 b0 = *(const float2*)&xs[j0][c];
            const float2 b1 = *(const float2*)&xs[j1][c];
            // sequential fma chain per accumulator — bit-exact vs v1
            c00 += a0.x * b0.x; c00 += a0.y * b0.y;
            c01 += a0.x * b1.x; c01 += a0.y * b1.y;
            c10 += a1.x * b0.x; c10 += a1.y * b0.y;
            c11 += a1.x * b1.x; c11 += a1.y * b1.y;
        }
        c00 *= (1.0f / (CC - 1)); c01 *= (1.0f / (CC - 1));
        c10 *= (1.0f / (CC - 1)); c11 *= (1.0f / (CC - 1));
        covm[i0][j0] = c00; covm[i0][j1] = c01;
        covm[i1][j0] = c10; covm[i1][j1] = c11;
        covm[j0][i0] = c00; covm[j1][i0] = c01;
        covm[j0][i1] = c10; covm[j1][i1] = c11;
    }
    __syncthreads();
    if (t < KK) stdv[t] = sqrtf(covm[t][t]);
    __syncthreads();
    #pragma unroll
    for (int k = 0; k < 4; ++k) {
        const int pair = t + k * 256;
        const int i = pair >> 5, j = pair & 31;
        adj_out[(size_t)bm * 1024 + pair] = covm[i][j] / (stdv[i] * stdv[j]);
    }
}

// ---------------------------------------------------------------------------
// Kernel 2: h[b][o][m] = gelu( sum_k A[o,k] * mean[b,k,m] ).  K=32 only.
// 1-wave blocks; A addresses are blockIdx/loop-derived -> s_load (uniform).
// ---------------------------------------------------------------------------
__global__ __launch_bounds__(64) void mlp1_kernel(
    const float* __restrict__ A_ws, const float* __restrict__ mean_ws,
    float* __restrict__ h_ws)
{
    const int m = threadIdx.x;
    const int b = blockIdx.y;
    const int ob = blockIdx.x * 4;
    float mr[32];
    #pragma unroll
    for (int k = 0; k < 32; ++k) mr[k] = mean_ws[(size_t)(b * 32 + k) * 64 + m];
    #pragma unroll
    for (int q = 0; q < 4; ++q) {
        const float* Ar = A_ws + (size_t)(ob + q) * 32;
        float a = 0.f;
        #pragma unroll
        for (int k = 0; k < 32; ++k) a += Ar[k] * mr[k];
        const float g = 0.5f * a * (1.0f + erff(a * 0.70710678118654752f));
        h_ws[(size_t)(b * 512 + ob + q) * 64 + m] = g;
    }
}

// ---------------------------------------------------------------------------
// Kernel 3: e[b][o][m] = sigmoid( sum_c W2[o,c] * h[b,c,m] ).  K=512.
// 1-wave blocks, No=4; W2 addresses uniform -> s_load_dwordx8; h coalesced.
// ---------------------------------------------------------------------------
__global__ __launch_bounds__(64) void mlp2_kernel(
    const float* __restrict__ W2, const float* __restrict__ h_ws,
    float* __restrict__ e_ws)
{
    const int m = threadIdx.x;
    const int b = blockIdx.y;
    const int ob = blockIdx.x * 4;
    const float* hb = h_ws + (size_t)b * 512 * 64 + m;
    const float* w0 = W2 + (size_t)(ob + 0) * 512;
    const float* w1 = W2 + (size_t)(ob + 1) * 512;
    const float* w2 = W2 + (size_t)(ob + 2) * 512;
    const float* w3 = W2 + (size_t)(ob + 3) * 512;
    float a0 = 0.f, a1 = 0.f, a2 = 0.f, a3 = 0.f;
    #pragma unroll 8
    for (int c = 0; c < 512; ++c) {
        const float hv = hb[(size_t)c * 64];
        a0 += w0[c] * hv; a1 += w1[c] * hv;
        a2 += w2[c] * hv; a3 += w3[c] * hv;
    }
    const float4 av = make_float4(a0, a1, a2, a3);
    const float* ap = &av.x;
    #pragma unroll
    for (int q = 0; q < 4; ++q) {
        const float e = 1.0f / (1.0f + expf(-ap[q]));
        e_ws[(size_t)(b * 1024 + ob + q) * 64 + m] = e;
    }
}

// ---------------------------------------------------------------------------
// Kernel 4: masked softmax (mask adj>0) + att @ x.  256 blocks (b,m).
// Register tiling: thread = (iq 0..7 -> 4 rows, c8 0..31 -> 2 float4 chunks).
// ---------------------------------------------------------------------------
__global__ __launch_bounds__(256) void softmax_out_kernel(
    const float* __restrict__ x, const float* __restrict__ e_ws,
    const float* __restrict__ adj, float* __restrict__ out)
{
    __shared__ float xs[KK][260];      // float4-aligned (260 % 4 == 0)
    __shared__ float att[KK][KK + 1];
    const int bm = blockIdx.x;
    const int b  = bm >> 6, m = bm & 63;
    const int t  = threadIdx.x;
    const float* xp = x + (size_t)bm * (KK * CC);

    #pragma unroll
    for (int s = 0; s < 8; ++s) {
        const int e = s * 1024 + t * 4;
        const float4 v = *(const float4*)(xp + e);
        *(float4*)&xs[e >> 8][e & 255] = v;
    }
    #pragma unroll
    for (int k = 0; k < 4; ++k) {
        const int pair = t + k * 256;
        const int i = pair >> 5, j = pair & 31;
        const float a  = adj[(size_t)bm * 1024 + pair];
        const float ev = e_ws[(size_t)(b * 1024 + pair) * 64 + m];
        att[i][j] = (a > 0.f) ? ev : -INFINITY;
    }
    __syncthreads();
    if (t < KK) {
        float mx = -INFINITY;
        #pragma unroll
        for (int j = 0; j < KK; ++j) mx = fmaxf(mx, att[t][j]);
        float s = 0.f;
        #pragma unroll
        for (int j = 0; j < KK; ++j) {
            const float v = expf(att[t][j] - mx);
            att[t][j] = v;
            s += v;
        }
        const float inv = 1.0f / s;
        #pragma unroll
        for (int j = 0; j < KK; ++j) att[t][j] *= inv;
    }
    __syncthreads();

    const int c8 = t & 31, iq = t >> 5;       // c chunks at 4*c8 and 128+4*c8
    const int i0 = iq * 4;
    const int cA = 4 * c8, cB = 128 + 4 * c8;
    float4 accA[4], accB[4];
    #pragma unroll
    for (int r = 0; r < 4; ++r) {
        accA[r] = make_float4(0.f, 0.f, 0.f, 0.f);
        accB[r] = make_float4(0.f, 0.f, 0.f, 0.f);
    }
    for (int j = 0; j < KK; ++j) {
        const float4 xa = *(const float4*)&xs[j][cA];
        const float4 xb = *(const float4*)&xs[j][cB];
        #pragma unroll
        for (int r = 0; r < 4; ++r) {
            const float av = att[i0 + r][j];
            accA[r].x += av * xa.x; accA[r].y += av * xa.y;
            accA[r].z += av * xa.z; accA[r].w += av * xa.w;
            accB[r].x += av * xb.x; accB[r].y += av * xb.y;
            accB[r].z += av * xb.z; accB[r].w += av * xb.w;
        }
    }
    float* op = out + (size_t)bm * (KK * CC);
    #pragma unroll
    for (int r = 0; r < 4; ++r) {
        *(float4*)(op + (size_t)(i0 + r) * CC + cA) = accA[r];
        *(float4*)(op + (size_t)(i0 + r) * CC + cB) = accB[r];
    }
}

extern "C" void kernel_launch(void* const* d_in, const int* in_sizes, int n_in,
                              void* d_out, int out_size, void* d_ws, size_t ws_size,
                              hipStream_t stream) {
    const float* x  = (const float*)d_in[0];   // (4,64,32,256)
    const float* W1 = (const float*)d_in[1];   // (512,1024)
    const float* W2 = (const float*)d_in[2];   // (1024,512)
    float* out     = (float*)d_out;                       // 2,097,152 floats
    float* adj_out = out + (size_t)4 * 64 * 32 * 256;     // +262,144 floats

    float* mean_ws = (float*)d_ws;                    // 4*32*64   =   8,192
    float* A_ws    = mean_ws + 8192;                  // 512*32    =  16,384
    float* h_ws    = A_ws + 16384;                    // 4*512*64  = 131,072
    float* e_ws    = h_ws + 131072;                   // 4*1024*64 = 262,144

    prep_kernel<<<768, 256, 0, stream>>>(x, W1, mean_ws, A_ws, adj_out);
    mlp1_kernel<<<dim3(128, 4), 64, 0, stream>>>(A_ws, mean_ws, h_ws);
    mlp2_kernel<<<dim3(256, 4), 64, 0, stream>>>(W2, h_ws, e_ws);
    softmax_out_kernel<<<256, 256, 0, stream>>>(x, e_ws, adj_out, out);
}

// Round 3
// 102.109 us; speedup vs baseline: 1.6345x; 1.0552x over previous
//
#include <hip/hip_runtime.h>
#include <math.h>

#define KK 32
#define CC 256

// ---------------------------------------------------------------------------
// Kernel 1 (fused): blocks 0..255 = per-(b,m) stats; blocks 256..767 = A-transform.
//
// Stats: stage x[b,m] (32x256) in LDS, row means, center, cov upper-tri via
// 2x2 register tiles (BIT-EXACT sequential fma chain per (i,j) — the adj>0
// mask is knife-edge, do NOT reassociate), adj to global, means to mean_ws.
//
// A-transform: A[o,k] = 0.5*rowsum_k(W1 row o) + colsum_k - 0.5*W1[o,33k],
// so that W1 @ p == A @ mean  (pooled_ij = (i==j)? m_i : 0.5*m_i + m_j).
// ---------------------------------------------------------------------------
__global__ __launch_bounds__(256) void prep_kernel(
    const float* __restrict__ x, const float* __restrict__ W1,
    float* __restrict__ mean_ws, float* __restrict__ A_ws,
    float* __restrict__ adj_out)
{
    __shared__ float xs[KK][258];      // 33 KB, stride 258: float2-aligned, 2-way banks
    __shared__ float part8[256];
    __shared__ float meanv[KK];
    __shared__ float covm[KK][KK + 1];
    __shared__ float stdv[KK];
    __shared__ float rowlds[1056];     // A-part: padded W1 row (33-stride 32-blocks)

    const int t = threadIdx.x;

    if (blockIdx.x >= 256) {
        // ---------------- A-transform: one W1 row per block ----------------
        const int o = blockIdx.x - 256;           // 0..511
        if (t < 64) {
            const float* wr = W1 + (size_t)o * 1024;
            #pragma unroll
            for (int u = 0; u < 4; ++u) {
                const int e = t * 16 + u * 4;
                const float4 v = *(const float4*)(wr + e);
                const int f = (e >> 5) * 33 + (e & 31);
                rowlds[f] = v.x; rowlds[f + 1] = v.y;
                rowlds[f + 2] = v.z; rowlds[f + 3] = v.w;
            }
        }
        __syncthreads();
        if (t < 32) {
            float rs = 0.f, cs = 0.f;
            #pragma unroll
            for (int j = 0; j < 32; ++j) rs += rowlds[t * 33 + j];
            #pragma unroll
            for (int i = 0; i < 32; ++i) cs += rowlds[i * 33 + t];
            const float diag = rowlds[t * 34];
            A_ws[o * 32 + t] = 0.5f * rs + cs - 0.5f * diag;
        }
        return;
    }

    // ---------------- per-(b,m) stats ----------------
    const int bm = blockIdx.x;            // 0..255
    const int b  = bm >> 6, m = bm & 63;
    const float* xp = x + (size_t)bm * (KK * CC);

    // stage: float4 global loads, scalar LDS stores (stride 258)
    #pragma unroll
    for (int s = 0; s < 8; ++s) {
        const int e = s * 1024 + t * 4;
        const float4 v = *(const float4*)(xp + e);
        const int i = e >> 8, col = e & 255;
        xs[i][col] = v.x; xs[i][col + 1] = v.y;
        xs[i][col + 2] = v.z; xs[i][col + 3] = v.w;
    }
    __syncthreads();

    // row sums -> means (identical reduction structure to the passing v1)
    {
        const int i = t >> 3, part = t & 7;
        float s = 0.f;
        const int c0 = part * 32;
        #pragma unroll
        for (int c = 0; c < 32; ++c) s += xs[i][c0 + c];
        part8[t] = s;
    }
    __syncthreads();
    if (t < KK) {
        float s = 0.f;
        #pragma unroll
        for (int k = 0; k < 8; ++k) s += part8[t * 8 + k];
        meanv[t] = s * (1.0f / CC);
        mean_ws[(size_t)(b * 32 + t) * 64 + m] = meanv[t];
    }
    __syncthreads();

    // center rows in place: cen = x - mean (same rounding as inline (xi-mi))
    {
        const int r = t >> 3, c0 = (t & 7) * 32;
        const float mv = meanv[r];
        #pragma unroll
        for (int c = 0; c < 32; ++c) xs[r][c0 + c] -= mv;
    }
    __syncthreads();

    // cov upper-triangle: 136 2x2 tiles, one per thread (t<136)
    if (t < 136) {
        int rem = t, r = 0;
        while (rem >= 16 - r) { rem -= 16 - r; ++r; }
        const int ti = r, tj = r + rem;
        const int i0 = 2 * ti, i1 = i0 + 1, j0 = 2 * tj, j1 = j0 + 1;
        float c00 = 0.f, c01 = 0.f, c10 = 0.f, c11 = 0.f;
        for (int c = 0; c < CC; c += 2) {
            const float2 a0 = *(const float2*)&xs[i0][c];
            const float2 a1 = *(const float2*)&xs[i1][c];
            const float2 b0 = *(const float2*)&xs[j0][c];
            const float2 b1 = *(const float2*)&xs[j1][c];
            // sequential fma chain per accumulator — bit-exact vs v1
            c00 += a0.x * b0.x; c00 += a0.y * b0.y;
            c01 += a0.x * b1.x; c01 += a0.y * b1.y;
            c10 += a1.x * b0.x; c10 += a1.y * b0.y;
            c11 += a1.x * b1.x; c11 += a1.y * b1.y;
        }
        c00 *= (1.0f / (CC - 1)); c01 *= (1.0f / (CC - 1));
        c10 *= (1.0f / (CC - 1)); c11 *= (1.0f / (CC - 1));
        covm[i0][j0] = c00; covm[i0][j1] = c01;
        covm[i1][j0] = c10; covm[i1][j1] = c11;
        covm[j0][i0] = c00; covm[j1][i0] = c01;
        covm[j0][i1] = c10; covm[j1][i1] = c11;
    }
    __syncthreads();
    if (t < KK) stdv[t] = sqrtf(covm[t][t]);
    __syncthreads();
    #pragma unroll
    for (int k = 0; k < 4; ++k) {
        const int pair = t + k * 256;
        const int i = pair >> 5, j = pair & 31;
        adj_out[(size_t)bm * 1024 + pair] = covm[i][j] / (stdv[i] * stdv[j]);
    }
}

// ---------------------------------------------------------------------------
// Kernel 2: h[b][o][m] = gelu( sum_k A[o,k] * mean[b,k,m] ).  K=32 only.
// 1-wave blocks; A addresses are blockIdx/loop-derived -> s_load (uniform).
// ---------------------------------------------------------------------------
__global__ __launch_bounds__(64) void mlp1_kernel(
    const float* __restrict__ A_ws, const float* __restrict__ mean_ws,
    float* __restrict__ h_ws)
{
    const int m = threadIdx.x;
    const int b = blockIdx.y;
    const int ob = blockIdx.x * 4;
    float mr[32];
    #pragma unroll
    for (int k = 0; k < 32; ++k) mr[k] = mean_ws[(size_t)(b * 32 + k) * 64 + m];
    #pragma unroll
    for (int q = 0; q < 4; ++q) {
        const float* Ar = A_ws + (size_t)(ob + q) * 32;
        float a = 0.f;
        #pragma unroll
        for (int k = 0; k < 32; ++k) a += Ar[k] * mr[k];
        const float g = 0.5f * a * (1.0f + erff(a * 0.70710678118654752f));
        h_ws[(size_t)(b * 512 + ob + q) * 64 + m] = g;
    }
}

// ---------------------------------------------------------------------------
// Kernel 3: e[b][o][m] = sigmoid( sum_c W2[o,c] * h[b,c,m] ).  K=512.
// NEW: block = 16 o x 64 m (4 waves), grid (64 o-tiles, 4 b) = 256 blocks.
// W2 tile (16x512 = 32 KB) staged in LDS; inner reads are wave-uniform
// float4 broadcasts (lane-identical address -> conflict-free). h read once
// per block, coalesced. Accumulation order per o is c-ascending — bit-exact
// vs the previous passing version.
// ---------------------------------------------------------------------------
__global__ __launch_bounds__(256) void mlp2_kernel(
    const float* __restrict__ W2, const float* __restrict__ h_ws,
    float* __restrict__ e_ws)
{
    __shared__ float W2s[16][512];     // 32 KB
    const int m  = threadIdx.x;        // 0..63
    const int ow = threadIdx.y;        // 0..3 (wave id)
    const int b  = blockIdx.y;
    const int ob = blockIdx.x * 16;    // o-tile base

    // stage W2[ob..ob+16, :] -> LDS, float4, fully coalesced
    {
        const int t = ow * 64 + m;     // 0..255
        const float* src = W2 + (size_t)ob * 512;
        #pragma unroll
        for (int u = 0; u < 8; ++u) {
            const int e4 = t + u * 256;            // float4 index 0..2047
            const float4 v = *(const float4*)(src + e4 * 4);
            *(float4*)&W2s[e4 >> 7][(e4 & 127) * 4] = v;
        }
    }
    __syncthreads();

    const float* hb = h_ws + (size_t)b * 512 * 64 + m;
    float acc[4] = {0.f, 0.f, 0.f, 0.f};
    const int ol = ow * 4;             // this thread's 4 o's: ob+ol .. ob+ol+3

    for (int c = 0; c < 512; c += 4) {
        const float hv0 = hb[(size_t)(c + 0) * 64];
        const float hv1 = hb[(size_t)(c + 1) * 64];
        const float hv2 = hb[(size_t)(c + 2) * 64];
        const float hv3 = hb[(size_t)(c + 3) * 64];
        #pragma unroll
        for (int q = 0; q < 4; ++q) {
            const float4 w = *(const float4*)&W2s[ol + q][c];  // broadcast
            // c-ascending chain per acc[q] — bit-exact
            acc[q] += w.x * hv0;
            acc[q] += w.y * hv1;
            acc[q] += w.z * hv2;
            acc[q] += w.w * hv3;
        }
    }
    #pragma unroll
    for (int q = 0; q < 4; ++q) {
        const int o = ob + ol + q;
        e_ws[(size_t)(b * 1024 + o) * 64 + m] = 1.0f / (1.0f + expf(-acc[q]));
    }
}

// ---------------------------------------------------------------------------
// Kernel 4: masked softmax (mask adj>0) + att @ x.  256 blocks (b,m).
// Register tiling: thread = (iq 0..7 -> 4 rows, c8 0..31 -> 2 float4 chunks).
// ---------------------------------------------------------------------------
__global__ __launch_bounds__(256) void softmax_out_kernel(
    const float* __restrict__ x, const float* __restrict__ e_ws,
    const float* __restrict__ adj, float* __restrict__ out)
{
    __shared__ float xs[KK][260];      // float4-aligned (260 % 4 == 0)
    __shared__ float att[KK][KK + 1];
    const int bm = blockIdx.x;
    const int b  = bm >> 6, m = bm & 63;
    const int t  = threadIdx.x;
    const float* xp = x + (size_t)bm * (KK * CC);

    #pragma unroll
    for (int s = 0; s < 8; ++s) {
        const int e = s * 1024 + t * 4;
        const float4 v = *(const float4*)(xp + e);
        *(float4*)&xs[e >> 8][e & 255] = v;
    }
    #pragma unroll
    for (int k = 0; k < 4; ++k) {
        const int pair = t + k * 256;
        const int i = pair >> 5, j = pair & 31;
        const float a  = adj[(size_t)bm * 1024 + pair];
        const float ev = e_ws[(size_t)(b * 1024 + pair) * 64 + m];
        att[i][j] = (a > 0.f) ? ev : -INFINITY;
    }
    __syncthreads();
    if (t < KK) {
        float mx = -INFINITY;
        #pragma unroll
        for (int j = 0; j < KK; ++j) mx = fmaxf(mx, att[t][j]);
        float s = 0.f;
        #pragma unroll
        for (int j = 0; j < KK; ++j) {
            const float v = expf(att[t][j] - mx);
            att[t][j] = v;
            s += v;
        }
        const float inv = 1.0f / s;
        #pragma unroll
        for (int j = 0; j < KK; ++j) att[t][j] *= inv;
    }
    __syncthreads();

    const int c8 = t & 31, iq = t >> 5;       // c chunks at 4*c8 and 128+4*c8
    const int i0 = iq * 4;
    const int cA = 4 * c8, cB = 128 + 4 * c8;
    float4 accA[4], accB[4];
    #pragma unroll
    for (int r = 0; r < 4; ++r) {
        accA[r] = make_float4(0.f, 0.f, 0.f, 0.f);
        accB[r] = make_float4(0.f, 0.f, 0.f, 0.f);
    }
    for (int j = 0; j < KK; ++j) {
        const float4 xa = *(const float4*)&xs[j][cA];
        const float4 xb = *(const float4*)&xs[j][cB];
        #pragma unroll
        for (int r = 0; r < 4; ++r) {
            const float av = att[i0 + r][j];
            accA[r].x += av * xa.x; accA[r].y += av * xa.y;
            accA[r].z += av * xa.z; accA[r].w += av * xa.w;
            accB[r].x += av * xb.x; accB[r].y += av * xb.y;
            accB[r].z += av * xb.z; accB[r].w += av * xb.w;
        }
    }
    float* op = out + (size_t)bm * (KK * CC);
    #pragma unroll
    for (int r = 0; r < 4; ++r) {
        *(float4*)(op + (size_t)(i0 + r) * CC + cA) = accA[r];
        *(float4*)(op + (size_t)(i0 + r) * CC + cB) = accB[r];
    }
}

extern "C" void kernel_launch(void* const* d_in, const int* in_sizes, int n_in,
                              void* d_out, int out_size, void* d_ws, size_t ws_size,
                              hipStream_t stream) {
    const float* x  = (const float*)d_in[0];   // (4,64,32,256)
    const float* W1 = (const float*)d_in[1];   // (512,1024)
    const float* W2 = (const float*)d_in[2];   // (1024,512)
    float* out     = (float*)d_out;                       // 2,097,152 floats
    float* adj_out = out + (size_t)4 * 64 * 32 * 256;     // +262,144 floats

    float* mean_ws = (float*)d_ws;                    // 4*32*64   =   8,192
    float* A_ws    = mean_ws + 8192;                  // 512*32    =  16,384
    float* h_ws    = A_ws + 16384;                    // 4*512*64  = 131,072
    float* e_ws    = h_ws + 131072;                   // 4*1024*64 = 262,144

    prep_kernel<<<768, 256, 0, stream>>>(x, W1, mean_ws, A_ws, adj_out);
    mlp1_kernel<<<dim3(128, 4), 64, 0, stream>>>(A_ws, mean_ws, h_ws);
    mlp2_kernel<<<dim3(64, 4), dim3(64, 4), 0, stream>>>(W2, h_ws, e_ws);
    softmax_out_kernel<<<256, 256, 0, stream>>>(x, e_ws, adj_out, out);
}